// Round 2
// baseline (237.490 us; speedup 1.0000x reference)
//
#include <hip/hip_runtime.h>
#include <hip/hip_bf16.h>

#define N_NODES 100000
#define N_EDGES 1250000
#define IN_DIM  128
#define HID     64
#define OUTD    16
#define ROW     64                 // padded CSR width (in-deg Poisson(12.5), max ~45)
#define NRANGE  8                  // XCD dst-range buckets
#define RSIZE   12500              // N_NODES / NRANGE
#define NCHUNK  128
#define CHUNK   9768               // ceil(N_EDGES/NCHUNK) rounded to x8 (int4-aligned)
#define FILLB   (NRANGE * NCHUNK)  // 1024 fill blocks
#define MTILE   128
#define GEMMB   ((N_NODES + MTILE - 1) / MTILE)   // 782

typedef __attribute__((ext_vector_type(8))) short  short8;   // 8 bf16 (4 VGPRs)
typedef __attribute__((ext_vector_type(4))) float  floatx4;  // MFMA acc
typedef __attribute__((ext_vector_type(4))) float  f32x4;    // nt-load/store friendly
typedef __attribute__((ext_vector_type(4))) int    i32x4;

__device__ __forceinline__ unsigned short f2bf(float f) {   // RNE bf16
    unsigned u = __float_as_uint(f);
    u += 0x7fffu + ((u >> 16) & 1u);
    return (unsigned short)(u >> 16);
}
__device__ __forceinline__ unsigned pk2(float lo, float hi) {  // v_cvt_pk_bf16_f32
    __hip_bfloat162 t = __float22bfloat162_rn(make_float2(lo, hi));
    return *reinterpret_cast<unsigned*>(&t);
}
__device__ __forceinline__ float bf2f_lo(unsigned u) { return __uint_as_float(u << 16); }
__device__ __forceinline__ float bf2f_hi(unsigned u) { return __uint_as_float(u & 0xffff0000u); }

// ---------------- zero cursor + dummy hb row ----------------
__global__ __launch_bounds__(256) void zero_cursor(int* __restrict__ cursor,
                                                   unsigned* __restrict__ hb_dummy) {
    int i = blockIdx.x * 256 + threadIdx.x;
    if (i < N_NODES) cursor[i] = 0;
    if (i < 32) hb_dummy[i] = 0u;          // 128B zero row (pull pad target)
}

// ------- fused: XCD-bucketed direct CSR fill + MFMA h = x@W1 (bf16, raw) ---
// Fill blocks [0,FILLB): range r = blockIdx&7 (consecutive blocks round-robin
// XCDs -> each 3.2MB csr range + cursor slice served by one XCD's L2).
// R14 = R13 with the hb row-stride bug fixed (s<<4, not s<<5).
// (1) dst AND src both read as unconditional nontemporal int4 -- removes the
// dependent scattered src gather from the kept-edge path; (2) x loads + hb
// stores nontemporal so streaming GEMM traffic stops evicting csr/cursor
// from L2. h stored UNSCALED: no degree dependency.
__global__ __launch_bounds__(256) void fill_gemm(const float* __restrict__ x,
                                                 const float* __restrict__ W1,
                                                 const int* __restrict__ src,
                                                 const int* __restrict__ dst,
                                                 int* __restrict__ cursor,
                                                 int* __restrict__ csr,
                                                 unsigned short* __restrict__ hb) {
    __shared__ unsigned short w1t[HID][132];   // [n][k] bf16, +132 pitch

    if (blockIdx.x < FILLB) {
        const int r  = blockIdx.x & 7;
        const int c  = blockIdx.x >> 3;
        const int lo = r * RSIZE;
        const int q1 = min(N_EDGES, (c + 1) * CHUNK) >> 2;
        for (int q = (c * CHUNK >> 2) + threadIdx.x; q < q1; q += 256) {
            i32x4 d4 = __builtin_nontemporal_load(((const i32x4*)dst) + q);
            i32x4 s4 = __builtin_nontemporal_load(((const i32x4*)src) + q);
#pragma unroll
            for (int u = 0; u < 4; u++) {
                int d = (u == 0) ? d4.x : (u == 1) ? d4.y : (u == 2) ? d4.z : d4.w;
                int s = (u == 0) ? s4.x : (u == 1) ? s4.y : (u == 2) ? s4.z : s4.w;
                if ((unsigned)(d - lo) < (unsigned)RSIZE) {
                    int p = atomicAdd(&cursor[d], 1);
                    if (p < ROW) csr[(size_t)d * ROW + p] = s;
                }
            }
        }
        return;
    }

    // ---- gemm part ----
    const int m0 = (blockIdx.x - FILLB) * MTILE;

    for (int q = threadIdx.x; q < IN_DIM * HID / 4; q += 256) {
        int k = q >> 4, n = (q & 15) * 4;
        float4 wq = ((const float4*)W1)[q];
        w1t[n + 0][k] = f2bf(wq.x);
        w1t[n + 1][k] = f2bf(wq.y);
        w1t[n + 2][k] = f2bf(wq.z);
        w1t[n + 3][k] = f2bf(wq.w);
    }
    __syncthreads();

    const int lane = threadIdx.x & 63;
    const int w    = threadIdx.x >> 6;
    const int mrow = lane & 15;
    const int quad = lane >> 4;
    const int rowa = min(m0 + w * 32 + mrow,      N_NODES - 1);
    const int rowb = min(m0 + w * 32 + 16 + mrow, N_NODES - 1);

    floatx4 acc[2][4] = {};
#pragma unroll
    for (int k0 = 0; k0 < IN_DIM; k0 += 32) {
        union { unsigned u[4]; short8 s; } a0, a1;
        {
            const f32x4* pa = (const f32x4*)(x + (size_t)rowa * IN_DIM + k0 + quad * 8);
            f32x4 u0 = __builtin_nontemporal_load(pa);
            f32x4 v0 = __builtin_nontemporal_load(pa + 1);
            a0.u[0] = pk2(u0.x, u0.y); a0.u[1] = pk2(u0.z, u0.w);
            a0.u[2] = pk2(v0.x, v0.y); a0.u[3] = pk2(v0.z, v0.w);
            const f32x4* pb = (const f32x4*)(x + (size_t)rowb * IN_DIM + k0 + quad * 8);
            f32x4 u1 = __builtin_nontemporal_load(pb);
            f32x4 v1 = __builtin_nontemporal_load(pb + 1);
            a1.u[0] = pk2(u1.x, u1.y); a1.u[1] = pk2(u1.z, u1.w);
            a1.u[2] = pk2(v1.x, v1.y); a1.u[3] = pk2(v1.z, v1.w);
        }
        short8 b0 = *(const short8*)&w1t[ 0 + mrow][k0 + quad * 8];
        short8 b1 = *(const short8*)&w1t[16 + mrow][k0 + quad * 8];
        short8 b2 = *(const short8*)&w1t[32 + mrow][k0 + quad * 8];
        short8 b3 = *(const short8*)&w1t[48 + mrow][k0 + quad * 8];
        acc[0][0] = __builtin_amdgcn_mfma_f32_16x16x32_bf16(a0.s, b0, acc[0][0], 0, 0, 0);
        acc[0][1] = __builtin_amdgcn_mfma_f32_16x16x32_bf16(a0.s, b1, acc[0][1], 0, 0, 0);
        acc[0][2] = __builtin_amdgcn_mfma_f32_16x16x32_bf16(a0.s, b2, acc[0][2], 0, 0, 0);
        acc[0][3] = __builtin_amdgcn_mfma_f32_16x16x32_bf16(a0.s, b3, acc[0][3], 0, 0, 0);
        acc[1][0] = __builtin_amdgcn_mfma_f32_16x16x32_bf16(a1.s, b0, acc[1][0], 0, 0, 0);
        acc[1][1] = __builtin_amdgcn_mfma_f32_16x16x32_bf16(a1.s, b1, acc[1][1], 0, 0, 0);
        acc[1][2] = __builtin_amdgcn_mfma_f32_16x16x32_bf16(a1.s, b2, acc[1][2], 0, 0, 0);
        acc[1][3] = __builtin_amdgcn_mfma_f32_16x16x32_bf16(a1.s, b3, acc[1][3], 0, 0, 0);
    }

    // D: row = w*32 + tm*16 + quad*4+reg, col = tn*16 + mrow (unscaled nt store)
#pragma unroll
    for (int tm = 0; tm < 2; tm++) {
#pragma unroll
        for (int reg = 0; reg < 4; reg++) {
            int m = m0 + w * 32 + tm * 16 + quad * 4 + reg;
            if (m < N_NODES) {
#pragma unroll
                for (int tn = 0; tn < 4; tn++)
                    __builtin_nontemporal_store(f2bf(acc[tm][tn][reg]),
                                                &hb[(size_t)m * HID + tn * 16 + mrow]);
            }
        }
    }
}

// ------- pull: weighted sum + bias/relu + W2 + log_softmax -----------------
// 16-edge rounds with 4 INDEPENDENT uint2 gathers in flight (was unroll-2 ->
// 2 dependent rounds typical). 87% of nodes (cnt+1<=16) finish the gather
// loop in ONE round. Self-loop folded into the pad lane (lane==cnt gets
// s=i, w=di): deletes the separate hs load, 4 self-FMAs and the tail branch.
// Pad lanes >cnt hit the zeroed dummy row with w=0.
// NOTE: hb row = HID(64) bf16 = 128B = 16 uint2 -> row stride shift is <<4.
__global__ __launch_bounds__(256) void pull_epilogue(const unsigned short* __restrict__ hb,
                                                     const int* __restrict__ csr,
                                                     const int* __restrict__ deg,
                                                     const float* __restrict__ b1,
                                                     const float* __restrict__ W2,
                                                     const float* __restrict__ b2,
                                                     float* __restrict__ out) {
    const int i     = blockIdx.x * 4 + (threadIdx.x >> 6);
    const int lane  = threadIdx.x & 63;
    const int e_sub = lane >> 4;   // 0..3
    const int f4    = lane & 15;   // bf16x4 slot of HID

    const int   dg  = deg[i];
    const int   cnt = min(dg, ROW - 1);   // <=63 so self fits in lane cnt (deg>63: P~0)
    const float di  = rsqrtf((float)dg + 1.0f);

    int   s_l = N_NODES;                                  // pad -> dummy zero row
    float w_l = 0.f;
    if (lane < cnt) {
        s_l = __builtin_nontemporal_load(csr + (size_t)i * ROW + lane);
        w_l = rsqrtf((float)deg[s_l] + 1.0f);             // L2-resident 4B gather
    } else if (lane == cnt) {
        s_l = i;                                          // folded self-loop
        w_l = di;
    }

    const uint2* hbv = (const uint2*)hb + f4;

    float ax = 0.f, ay = 0.f, az = 0.f, aw = 0.f;
    const int R = (cnt + 16) >> 4;        // ceil((cnt+1)/16) rounds of 16 edges
    for (int r = 0; r < R; ++r) {
        const int e0 = (r << 4) + e_sub;  // edges e0, e0+4, e0+8, e0+12
        int   s0 = __shfl(s_l, e0,      64), s1 = __shfl(s_l, e0 + 4,  64);
        int   s2 = __shfl(s_l, e0 + 8,  64), s3 = __shfl(s_l, e0 + 12, 64);
        float w0 = __shfl(w_l, e0,      64), w1 = __shfl(w_l, e0 + 4,  64);
        float w2 = __shfl(w_l, e0 + 8,  64), w3 = __shfl(w_l, e0 + 12, 64);
        uint2 a = hbv[s0 << 4];           // 4 independent gathers in flight
        uint2 b = hbv[s1 << 4];
        uint2 c = hbv[s2 << 4];
        uint2 d = hbv[s3 << 4];
        ax = fmaf(bf2f_lo(a.x), w0, ax); ay = fmaf(bf2f_hi(a.x), w0, ay);
        az = fmaf(bf2f_lo(a.y), w0, az); aw = fmaf(bf2f_hi(a.y), w0, aw);
        ax = fmaf(bf2f_lo(b.x), w1, ax); ay = fmaf(bf2f_hi(b.x), w1, ay);
        az = fmaf(bf2f_lo(b.y), w1, az); aw = fmaf(bf2f_hi(b.y), w1, aw);
        ax = fmaf(bf2f_lo(c.x), w2, ax); ay = fmaf(bf2f_hi(c.x), w2, ay);
        az = fmaf(bf2f_lo(c.y), w2, az); aw = fmaf(bf2f_hi(c.y), w2, aw);
        ax = fmaf(bf2f_lo(d.x), w3, ax); ay = fmaf(bf2f_hi(d.x), w3, ay);
        az = fmaf(bf2f_lo(d.y), w3, az); aw = fmaf(bf2f_hi(d.y), w3, aw);
    }

    // combine the 4 edge groups -> every lane holds the full slice sum
    ax += __shfl_xor(ax, 16, 64); ax += __shfl_xor(ax, 32, 64);
    ay += __shfl_xor(ay, 16, 64); ay += __shfl_xor(ay, 32, 64);
    az += __shfl_xor(az, 16, 64); az += __shfl_xor(az, 32, 64);
    aw += __shfl_xor(aw, 16, 64); aw += __shfl_xor(aw, 32, 64);

    // x di, + b1, relu (self already included with weight di)
    float4 b1v = ((const float4*)b1)[f4];
    float v0 = fmaxf(fmaf(ax, di, b1v.x), 0.f);
    float v1 = fmaxf(fmaf(ay, di, b1v.y), 0.f);
    float v2 = fmaxf(fmaf(az, di, b1v.z), 0.f);
    float v3 = fmaxf(fmaf(aw, di, b1v.w), 0.f);

    // W2: lane covers hid slice [4*f4,4*f4+4) x out slice [4*e_sub,4*e_sub+4)
    const float4* W2v = (const float4*)W2;         // [HID][OUTD/4] float4 view
    float4 w0 = W2v[(4 * f4 + 0) * 4 + e_sub];
    float4 w1 = W2v[(4 * f4 + 1) * 4 + e_sub];
    float4 w2 = W2v[(4 * f4 + 2) * 4 + e_sub];
    float4 w3 = W2v[(4 * f4 + 3) * 4 + e_sub];
    float p0 = v0 * w0.x + v1 * w1.x + v2 * w2.x + v3 * w3.x;
    float p1 = v0 * w0.y + v1 * w1.y + v2 * w2.y + v3 * w3.y;
    float p2 = v0 * w0.z + v1 * w1.z + v2 * w2.z + v3 * w3.z;
    float p3 = v0 * w0.w + v1 * w1.w + v2 * w2.w + v3 * w3.w;
#pragma unroll
    for (int d = 1; d < 16; d <<= 1) {
        p0 += __shfl_xor(p0, d, 64);
        p1 += __shfl_xor(p1, d, 64);
        p2 += __shfl_xor(p2, d, 64);
        p3 += __shfl_xor(p3, d, 64);
    }
    float4 b2v = ((const float4*)b2)[e_sub];
    float lg0 = p0 + b2v.x, lg1 = p1 + b2v.y, lg2 = p2 + b2v.z, lg3 = p3 + b2v.w;

    // log_softmax over 16 logits spread across e_sub groups
    float m = fmaxf(fmaxf(lg0, lg1), fmaxf(lg2, lg3));
    m = fmaxf(m, __shfl_xor(m, 16, 64));
    m = fmaxf(m, __shfl_xor(m, 32, 64));
    float s = __expf(lg0 - m) + __expf(lg1 - m) + __expf(lg2 - m) + __expf(lg3 - m);
    s += __shfl_xor(s, 16, 64);
    s += __shfl_xor(s, 32, 64);
    float lse = __logf(s) + m;

    if (f4 == 0) {
        f32x4 o = {lg0 - lse, lg1 - lse, lg2 - lse, lg3 - lse};
        __builtin_nontemporal_store(o, ((f32x4*)out) + (size_t)i * 4 + e_sub);
    }
}

extern "C" void kernel_launch(void* const* d_in, const int* in_sizes, int n_in,
                              void* d_out, int out_size, void* d_ws, size_t ws_size,
                              hipStream_t stream) {
    const float* x   = (const float*)d_in[0];
    const int*   ei  = (const int*)d_in[1];    // int64 in ref -> int32 here
    const float* W1  = (const float*)d_in[2];
    const float* b1  = (const float*)d_in[3];
    const float* W2  = (const float*)d_in[4];
    const float* b2  = (const float*)d_in[5];
    float*       out = (float*)d_out;

    const int* src = ei;             // edge_index[0]
    const int* dst = ei + N_EDGES;   // edge_index[1]

    char* ws = (char*)d_ws;
    size_t off = 0;
    unsigned short* hb = (unsigned short*)(ws + off);
    off += (size_t)(N_NODES + 1) * HID * 2;                                       // 12.8 MB (+pad row)
    int*   csr    = (int*)  (ws + off); off += ((size_t)N_NODES * ROW + ROW) * 4; // 25.6 MB
    int*   cursor = (int*)  (ws + off); off += (size_t)N_NODES * 4;               // 400 KB

    zero_cursor<<<(N_NODES + 255) / 256, 256, 0, stream>>>(
        cursor, (unsigned*)(hb + (size_t)N_NODES * HID));
    fill_gemm<<<FILLB + GEMMB, 256, 0, stream>>>(x, W1, src, dst, cursor, csr, hb);
    pull_epilogue<<<N_NODES / 4, 256, 0, stream>>>(hb, csr, cursor, b1, W2, b2, out);
}